// Round 2
// baseline (262.149 us; speedup 1.0000x reference)
//
#include <hip/hip_runtime.h>

// PhysicsPriorGenerator: out[prior][b][j][a] = exp(-2*(DEPTHS[j]-dt)^2) * inv_denom
//   dt = d / cos((theta_p + ANGLES[a]) * pi/180);  valid = 0 < dt < 50
// Key: sigma=0.5 vs depth step 50/511=0.098 -> Gaussian is numerically zero
// (<2.5e-10, far below 4.88e-4 tol) beyond ~34 depth indices from center.
// So: banded phase-1 column sums (65 rows not 512), and phase-2 only computes
// exp inside the block-wide band [min_c-34, max_c+34]; everything else is a
// pure float4 zero store. inv_denom is folded into the exp2 argument:
//   v = exp2(K2*dx*dx + log2(1/sum)),  K2 = -2*log2(e)
// Grid split 2x along depth (1024 blocks) for 4 blocks/CU -> 16 waves/CU.
// NOTE: __exp2f/__log2f collide with glibc math.h macros on this toolchain;
// use the AMDGPU builtins directly (v_exp_f32 is 2^x, v_log_f32 is log2).

#define DD 512
#define AA 256
#define DSTEP (50.0f / 511.0f)
#define K2 (-2.8853900817779268f)   // -2 * log2(e)
#define BHW 34                      // write-band half-width in depth indices

__device__ __forceinline__ float fexp2(float x) { return __builtin_amdgcn_exp2f(x); }
__device__ __forceinline__ float flog2(float x) { return __builtin_amdgcn_logf(x); }

__global__ __launch_bounds__(256) void prior_kernel(const float* __restrict__ p0,
                                                    const float* __restrict__ p1,
                                                    float* __restrict__ out) {
    const int bh   = blockIdx.x;     // 0..1023
    const int blk  = bh >> 1;        // prior*256 + b
    const int half = bh & 1;         // which 256-row depth half
    const int b    = blk & 255;
    const float* __restrict__ pp = (blk < 256) ? p0 : p1;

    __shared__ __align__(16) float dt_s[AA];
    __shared__ __align__(16) float li_s[AA];
    __shared__ int jlo_s, jhi_s;

    const int t = threadIdx.x;
    if (t == 0) { jlo_s = 1 << 30; jhi_s = -(1 << 30); }
    __syncthreads();

    const float d  = pp[b * 3 + 1];
    const float th = pp[b * 3 + 2];

    // ---- Phase 1: per-angle banded column sum -> li = log2(1/sum) ----
    {
        const int a = t;
        const float ang = -30.0f + (float)a * (60.0f / 255.0f);
        const float rad = (th + ang) * 0.017453292519943295f;  // pi/180 (fp32)
        float dt = d / cosf(rad);
        const bool valid = (dt > 0.0f) && (dt < 50.0f);
        float li = 0.0f;
        if (valid) {
            const int c  = (int)(dt * (511.0f / 50.0f) + 0.5f);  // center row
            const int lo = max(0, c - 32);
            const int hi = min(DD - 1, c + 32);
            float sum = 0.0f;
            for (int j = lo; j <= hi; ++j) {
                const float dep = (float)j * DSTEP;
                const float dx  = dep - dt;
                sum += fexp2(K2 * dx * dx);
            }
            li = -flog2(sum);            // log2(inv_denom); sum >= ~1 here
            atomicMin(&jlo_s, c);
            atomicMax(&jhi_s, c);
        } else {
            dt = 1.0e5f;   // K2*dx*dx ~ -2.9e10 -> exp2 -> exact 0, no inf/nan
        }
        dt_s[a] = dt;
        li_s[a] = li;
    }
    __syncthreads();

    // ---- Phase 2: wave-uniform banding, float4 stores along angle ----
    // thread t -> angles 4*(t&63)..+3, rows [half*256 + (t>>6)*64, +64)
    const int a4 = (t & 63) * 4;
    const float4 dtv = *(const float4*)&dt_s[a4];
    const float4 liv = *(const float4*)&li_s[a4];

    const int jq0 = half * 256 + (t >> 6) * 64;
    const int jq1 = jq0 + 64;
    // clamp band to this wave's row range; guarantee jq0 <= lo <= hi <= jq1
    const int lo = max(jq0, min(jq1, jlo_s - BHW));
    const int hi = max(lo,  min(jq1, jhi_s + BHW + 1));

    float* __restrict__ outp = out + (size_t)blk * (DD * AA) + a4;
    const float4 zero = {0.0f, 0.0f, 0.0f, 0.0f};

    for (int j = jq0; j < lo; ++j)
        *(float4*)(outp + (size_t)j * AA) = zero;

    float jf = (float)lo;   // exact integer float; dep = jf*DSTEP matches ref
    for (int j = lo; j < hi; ++j, jf += 1.0f) {
        const float dep = jf * DSTEP;
        float4 v;
        float dx;
        dx = dep - dtv.x; v.x = fexp2(__fmaf_rn(K2 * dx, dx, liv.x));
        dx = dep - dtv.y; v.y = fexp2(__fmaf_rn(K2 * dx, dx, liv.y));
        dx = dep - dtv.z; v.z = fexp2(__fmaf_rn(K2 * dx, dx, liv.z));
        dx = dep - dtv.w; v.w = fexp2(__fmaf_rn(K2 * dx, dx, liv.w));
        *(float4*)(outp + (size_t)j * AA) = v;
    }

    for (int j = hi; j < jq1; ++j)
        *(float4*)(outp + (size_t)j * AA) = zero;
}

extern "C" void kernel_launch(void* const* d_in, const int* in_sizes, int n_in,
                              void* d_out, int out_size, void* d_ws, size_t ws_size,
                              hipStream_t stream) {
    const float* p0 = (const float*)d_in[0];   // p        (256 x 3)
    const float* p1 = (const float*)d_in[1];   // p_calib  (256 x 3)
    float* out = (float*)d_out;                // 2 x 256 x 512 x 256 fp32
    prior_kernel<<<dim3(2 * 2 * 256), dim3(256), 0, stream>>>(p0, p1, out);
}